// Round 12
// baseline (136.052 us; speedup 1.0000x reference)
//
#include <hip/hip_runtime.h>

#define NPTS   131072
#define CIN    32
#define KPL    2048
#define NLEAF  64
#define NB1    8
#define DPJ    128
#define DHID   256
#define DOUT   512
#define TM     128         // points per block in the leaf kernel

typedef __attribute__((ext_vector_type(8))) short  short8;
typedef __attribute__((ext_vector_type(4))) float  f32x4;

// round-to-nearest-even f32 -> bf16
__device__ __forceinline__ unsigned short f2bf(float x) {
    unsigned u = __float_as_uint(x);
    u += 0x7FFFu + ((u >> 16) & 1u);
    return (unsigned short)(u >> 16);
}

// ---------------------------------------------------------------------------
// Weight conversion pre-pass: f32 (K x N) -> bf16 transposed (N x K)
//   wp1t[128][32], wp2t[128][128], we1t[256][128] (rows 3..130 of We1), we2t[512][256]
// ---------------------------------------------------------------------------
__global__ __launch_bounds__(256) void convert_weights(
    const float* __restrict__ Wp1, const float* __restrict__ Wp2,
    const float* __restrict__ We1, const float* __restrict__ We2,
    unsigned short* __restrict__ wp1t, unsigned short* __restrict__ wp2t,
    unsigned short* __restrict__ we1t, unsigned short* __restrict__ we2t)
{
    int idx = blockIdx.x * 256 + threadIdx.x;
    if (idx < 4096) {                       // Wp1: 32 x 128
        int n = idx / 32, k = idx % 32;
        wp1t[idx] = f2bf(Wp1[k * DPJ + n]);
    } else if (idx < 20480) {               // Wp2: 128 x 128
        int i = idx - 4096;
        int n = i / 128, k = i % 128;
        wp2t[i] = f2bf(Wp2[k * DPJ + n]);
    } else if (idx < 53248) {               // We1 rows 3..130: 128 x 256
        int i = idx - 20480;
        int n = i / 128, k = i % 128;
        we1t[i] = f2bf(We1[(k + 3) * DHID + n]);
    } else if (idx < 184320) {              // We2: 256 x 512
        int i = idx - 53248;
        int n = i / 256, k = i % 256;
        we2t[i] = f2bf(We2[k * DOUT + n]);
    }
}

// ---------------------------------------------------------------------------
// MFMA GEMM core: acc[MF][NF] (+bias) += A(LDS, swizzled bf16) @ Wt(global, N x K bf16)
// A-frag: row = rb0 + 16m + (lane&15), k contiguous.  B-frag: col = cb + 16n + (lane&15).
// Plain loads: R6 proved the compiler already hoists all B-loads of a fully
// unrolled call into one issue group (explicit 2-slot pipeline was NULL).
// ---------------------------------------------------------------------------
template<int MF, int NF, int KSTEPS, int SB, int WK>
__device__ __forceinline__ void gemm_core(
    const char* sIn, const unsigned short* __restrict__ wt,
    const float* __restrict__ bias, int rb0, int cb, int lr, int lg, f32x4 acc[MF][NF])
{
    #pragma unroll
    for (int n = 0; n < NF; ++n) {
        float bv = bias[cb + 16 * n + lr];
        #pragma unroll
        for (int m = 0; m < MF; ++m) acc[m][n] = f32x4{bv, bv, bv, bv};
    }
    #pragma unroll
    for (int kk = 0; kk < KSTEPS; ++kk) {
        short8 b[NF];
        #pragma unroll
        for (int n = 0; n < NF; ++n)
            b[n] = *reinterpret_cast<const short8*>(
                wt + (size_t)(cb + 16 * n + lr) * WK + kk * 32 + lg * 8);
        #pragma unroll
        for (int m = 0; m < MF; ++m) {
            int row  = rb0 + 16 * m + lr;
            int byte = (row * SB + kk * 64 + lg * 16) ^ ((row & 7) << 4);
            short8 a = *reinterpret_cast<const short8*>(sIn + byte);
            #pragma unroll
            for (int n = 0; n < NF; ++n)
                acc[m][n] = __builtin_amdgcn_mfma_f32_16x16x32_bf16(a, b[n], acc[m][n], 0, 0, 0);
        }
    }
}

// store acc to swizzled bf16 LDS buffer; D mapping row = rb0+16m+lg*4+r, col = cb+16n+lr
template<int MF, int NF, int SB, bool RELU>
__device__ __forceinline__ void store_frag(char* sOut, int rb0, int cb, int lr, int lg, f32x4 acc[MF][NF])
{
    #pragma unroll
    for (int m = 0; m < MF; ++m) {
        #pragma unroll
        for (int r = 0; r < 4; ++r) {
            int row = rb0 + 16 * m + lg * 4 + r;
            int rb  = row * SB;
            int sw  = (row & 7) << 4;
            #pragma unroll
            for (int n = 0; n < NF; ++n) {
                float v = acc[m][n][r];
                if (RELU) v = fmaxf(v, 0.f);
                int byte = (rb + (cb + 16 * n + lr) * 2) ^ sw;
                *reinterpret_cast<unsigned short*>(sOut + byte) = f2bf(v);
            }
        }
    }
}

// max-reduce an acc[MF][NF] block over rows and write to leaf accumulator
// (cross-wave row halves merge via atomicMax on the same columns)
template<int MF, int NF>
__device__ __forceinline__ void pool_frag(float* dst, int cb, int lr, int lg, f32x4 acc[MF][NF])
{
    #pragma unroll
    for (int n = 0; n < NF; ++n) {
        float vm = 0.f;   // relu folded into max with 0
        #pragma unroll
        for (int m = 0; m < MF; ++m) {
            #pragma unroll
            for (int r = 0; r < 4; ++r) vm = fmaxf(vm, acc[m][n][r]);
        }
        vm = fmaxf(vm, __shfl_xor(vm, 16));
        vm = fmaxf(vm, __shfl_xor(vm, 32));
        if (lg == 0)
            atomicMax(reinterpret_cast<int*>(dst + cb + 16 * n + lr),
                      __float_as_int(vm));
    }
}

// ---------------------------------------------------------------------------
// Fused per-point pipeline + leaf max-pool, bf16 MFMA.
// grid = NLEAF * (KPL/TM) = 1024 blocks, **512 threads (8 waves, 2M x 4N)**.
// R11 (TM=128, 4 waves): leaf ~98us at 1 wave/SIMD; MfmaUtil 20% matches the
// single-wave MFMA issue floor, the rest is un-overlapped dependent-chain
// stall. R8 evidence: 2 waves/SIMD cut per-slot cost 23% (MFMA pipe of one
// wave overlaps VALU/LDS/load latency of the other - m114 co-schedule).
// This round keeps TM=128 but splits M across 2 wave-groups: each wave
// MF=4, NF=2 (R8's register shape, <=128 arch VGPR - fits the 512-thread
// compiler cap that MF=8 broke in R10). LDS ~101 KB -> 1 block/CU, 8 waves
// = 2 waves/SIMD. M-split doubles per-block B-loads (9%-scale effect per
// R11) to buy wave-interleave (23%-scale effect per R8).
// ---------------------------------------------------------------------------
__global__ __launch_bounds__(512, 1) void leaf_mfma_kernel(
    const float* __restrict__ coords, const float* __restrict__ feats,
    const int* __restrict__ leaf_indices, const int* __restrict__ leaf_center_idx,
    const unsigned short* __restrict__ wp1t, const float* __restrict__ bp1,
    const unsigned short* __restrict__ wp2t, const float* __restrict__ bp2,
    const unsigned short* __restrict__ we1t, const float* __restrict__ be1,
    const float* __restrict__ We1raw,
    const unsigned short* __restrict__ we2t, const float* __restrict__ be2,
    float* __restrict__ leaf_out)              // = out + (1+NB1)*DOUT, zero-initialized
{
    __shared__ __align__(16) char bufH [TM * DHID * 2];   // 64 KB
    __shared__ __align__(16) char bufP2[TM * DPJ * 2];    // 32 KB
    __shared__ float s_rel[TM][4];                        // 2 KB
    __shared__ float s_we1rel[3 * DHID];                  // 3 KB

    const int t    = threadIdx.x;
    const int lane = t & 63;
    const int w    = t >> 6;       // wave id 0..7
    const int wm   = w >> 2;       // M-group 0..1 (rows wm*64 .. wm*64+63)
    const int wn   = w & 3;        // N-group 0..3
    const int rb0  = wm * 64;
    const int lr   = lane & 15;
    const int lg   = lane >> 4;

    const int l     = blockIdx.x >> 4;          // leaf (16 chunks/leaf)
    const int chunk = blockIdx.x & 15;
    const int base  = l * KPL + chunk * TM;

    // stage features -> bf16 LDS (swizzled): 512 threads, 16B (8 ch) per thread
    {
        const int p  = t >> 2;          // 0..127
        const int kq = (t & 3) << 3;    // 0,8,16,24
        const int gi = leaf_indices[base + p];
        const float* src = feats + (size_t)gi * CIN + kq;
        float4 v0 = *reinterpret_cast<const float4*>(src);
        float4 v1 = *reinterpret_cast<const float4*>(src + 4);
        short8 o;
        o[0] = (short)f2bf(v0.x); o[1] = (short)f2bf(v0.y);
        o[2] = (short)f2bf(v0.z); o[3] = (short)f2bf(v0.w);
        o[4] = (short)f2bf(v1.x); o[5] = (short)f2bf(v1.y);
        o[6] = (short)f2bf(v1.z); o[7] = (short)f2bf(v1.w);
        int byte = (p * (CIN * 2) + kq * 2) ^ ((p & 7) << 4);
        *reinterpret_cast<short8*>(bufH + byte) = o;
    }
    if (t < TM) {
        const int gi = leaf_indices[base + t];
        const int ci = leaf_center_idx[l];
        s_rel[t][0] = coords[gi * 3 + 0] - coords[ci * 3 + 0];
        s_rel[t][1] = coords[gi * 3 + 1] - coords[ci * 3 + 1];
        s_rel[t][2] = coords[gi * 3 + 2] - coords[ci * 3 + 2];
    }
    if (t < DHID) {
        #pragma unroll
        for (int j = 0; j < 3; ++j) s_we1rel[j * DHID + t] = We1raw[j * DHID + t];
    }
    __syncthreads();

    // ---- Stage 1: P1 = relu(X @ Wp1 + bp1)   (128x128, K=32; 64r x 32c per wave) ----
    {
        f32x4 acc[4][2];
        gemm_core<4, 2, 1, CIN * 2, 32>(bufH, wp1t, bp1, rb0, wn * 32, lr, lg, acc);
        store_frag<4, 2, DPJ * 2, true>(bufH + TM * CIN * 2, rb0, wn * 32, lr, lg, acc);
    }
    __syncthreads();

    // ---- Stage 2: P2 = P1 @ Wp2 + bp2        (128x128, K=128; 64r x 32c per wave) ----
    {
        f32x4 acc[4][2];
        gemm_core<4, 2, 4, DPJ * 2, 128>(bufH + TM * CIN * 2, wp2t, bp2, rb0, wn * 32, lr, lg, acc);
        store_frag<4, 2, DPJ * 2, false>(bufP2, rb0, wn * 32, lr, lg, acc);
    }
    __syncthreads();

    // ---- Stage 3: H = relu([rel,P2] @ We1 + be1)  (128x256; 64r x 64c per wave) ----
    // two passes of 32 cols keep peak acc at 32 regs
    #pragma unroll
    for (int p3 = 0; p3 < 2; ++p3) {
        const int cb = wn * 64 + p3 * 32;
        f32x4 acc[4][2];
        gemm_core<4, 2, 4, DPJ * 2, 128>(bufP2, we1t, be1, rb0, cb, lr, lg, acc);
        // rel (K=3) contribution on VALU
        #pragma unroll
        for (int m = 0; m < 4; ++m) {
            #pragma unroll
            for (int r = 0; r < 4; ++r) {
                int row = rb0 + 16 * m + lg * 4 + r;
                float r0 = s_rel[row][0], r1 = s_rel[row][1], r2 = s_rel[row][2];
                #pragma unroll
                for (int n = 0; n < 2; ++n) {
                    int col = cb + 16 * n + lr;
                    acc[m][n][r] += r0 * s_we1rel[col]
                                  + r1 * s_we1rel[DHID + col]
                                  + r2 * s_we1rel[2 * DHID + col];
                }
            }
        }
        store_frag<4, 2, DHID * 2, true>(bufH, rb0, cb, lr, lg, acc);
    }
    __syncthreads();

    // ---- Stage 4: out = relu(H @ We2 + be2) (128x512; 64r x 128c per wave) ----
    // four passes of 32 cols keep peak acc at 32 regs
    {
        float* const dst = leaf_out + (size_t)l * DOUT;
        #pragma unroll
        for (int p4 = 0; p4 < 4; ++p4) {
            const int cb = wn * 128 + p4 * 32;
            f32x4 acc[4][2];
            gemm_core<4, 2, 8, DHID * 2, 256>(bufH, we2t, be2, rb0, cb, lr, lg, acc);
            pool_frag<4, 2>(dst, cb, lr, lg, acc);
        }
    }
}

// ---------------------------------------------------------------------------
// Aggregator, phase 1 (pool): pooled[p][col] = max_m relu(z_m . Wa1[:,col] + ba1[col])
//   z_m = [child[p*8+m][0:512], coords[child_idx[p*8+m]] - coords[parent_idx[p]]]
// grid = nparent*8 blocks (8 col-chunks of 64), 256 threads (4-way K split).
// ---------------------------------------------------------------------------
__global__ __launch_bounds__(256) void agg_pool_kernel(
    const float* __restrict__ child,      // [nparent*8][512]
    const float* __restrict__ coords,
    const int* __restrict__ child_idx,    // [nparent*8]
    const int* __restrict__ parent_idx,   // [nparent]
    const float* __restrict__ Wa1, const float* __restrict__ ba1,
    float* __restrict__ pooled)           // [nparent][512]
{
    __shared__ float s_z[NB1][516];       // 8 children x (512 feat + 3 rel)
    __shared__ float s_red[4][NB1][64];

    const int t  = threadIdx.x;
    const int b  = blockIdx.x;
    const int p  = b >> 3, cc = b & 7;
    const int c  = t & 63;
    const int col = cc * 64 + c;
    const int ks = t >> 6;                // K-slice 0..3

    {   // stage child features (8 x 512 f32)
        const int m = t >> 5, tt = t & 31;
        const float* src = child + (size_t)(p * NB1 + m) * DOUT;
        #pragma unroll
        for (int i = 0; i < 4; ++i) {
            const int idx = (i * 32 + tt) * 4;
            *reinterpret_cast<float4*>(&s_z[m][idx]) =
                *reinterpret_cast<const float4*>(src + idx);
        }
    }
    if (t < 24) {                         // rel coords into rows 512..514
        const int m = t / 3, j = t % 3;
        s_z[m][512 + j] = coords[child_idx[p * NB1 + m] * 3 + j]
                        - coords[parent_idx[p] * 3 + j];
    }
    __syncthreads();

    float acc[NB1] = {0.f, 0.f, 0.f, 0.f, 0.f, 0.f, 0.f, 0.f};
    const int k0 = ks * 128;
    #pragma unroll 32
    for (int i = 0; i < 128; ++i) {
        const int k = k0 + i;
        const float wv = Wa1[(size_t)k * DOUT + col];
        #pragma unroll
        for (int m = 0; m < NB1; ++m) acc[m] += s_z[m][k] * wv;
    }
    if (ks == 3) {                        // rel rows 512..514
        #pragma unroll
        for (int k = 512; k < 515; ++k) {
            const float wv = Wa1[(size_t)k * DOUT + col];
            #pragma unroll
            for (int m = 0; m < NB1; ++m) acc[m] += s_z[m][k] * wv;
        }
    }
    #pragma unroll
    for (int m = 0; m < NB1; ++m) s_red[ks][m][c] = acc[m];
    __syncthreads();

    if (t < 64) {
        const float bv = ba1[col];
        float pm = 0.f;                   // relu folded into max with 0
        #pragma unroll
        for (int m = 0; m < NB1; ++m) {
            float v = bv + s_red[0][m][c] + s_red[1][m][c]
                         + s_red[2][m][c] + s_red[3][m][c];
            pm = fmaxf(pm, v);
        }
        pooled[(size_t)p * DOUT + col] = pm;
    }
}

// ---------------------------------------------------------------------------
// Aggregator, phase 2 (matvec): outrow[p][col] = pooled[p] . Wa2[:,col] + ba2[col]
// grid = nparent*8 blocks, 256 threads (4-way K split).
// ---------------------------------------------------------------------------
__global__ __launch_bounds__(256) void agg_out_kernel(
    const float* __restrict__ pooled,     // [nparent][512]
    const float* __restrict__ Wa2, const float* __restrict__ ba2,
    float* __restrict__ outbase)          // row p at outbase + p*DOUT
{
    __shared__ float s_p[DOUT];
    __shared__ float s_red[4][64];

    const int t  = threadIdx.x;
    const int b  = blockIdx.x;
    const int p  = b >> 3, cc = b & 7;
    const int c  = t & 63;
    const int col = cc * 64 + c;
    const int ks = t >> 6;

    if (t < 128)
        *reinterpret_cast<float4*>(&s_p[t * 4]) =
            *reinterpret_cast<const float4*>(pooled + (size_t)p * DOUT + t * 4);
    __syncthreads();

    float acc = 0.f;
    const int k0 = ks * 128;
    #pragma unroll 32
    for (int i = 0; i < 128; ++i) {
        const int k = k0 + i;
        acc += s_p[k] * Wa2[(size_t)k * DOUT + col];
    }
    s_red[ks][c] = acc;
    __syncthreads();

    if (t < 64)
        outbase[(size_t)p * DOUT + col] =
            ba2[col] + s_red[0][c] + s_red[1][c] + s_red[2][c] + s_red[3][c];
}

extern "C" void kernel_launch(void* const* d_in, const int* in_sizes, int n_in,
                              void* d_out, int out_size, void* d_ws, size_t ws_size,
                              hipStream_t stream)
{
    const float* coords          = (const float*)d_in[0];
    const float* feats           = (const float*)d_in[1];
    const int*   leaf_indices    = (const int*)d_in[2];
    const int*   leaf_center_idx = (const int*)d_in[3];
    const int*   l1_center_idx   = (const int*)d_in[4];
    const int*   root_center_idx = (const int*)d_in[5];
    const float* Wp1 = (const float*)d_in[6];
    const float* bp1 = (const float*)d_in[7];
    const float* Wp2 = (const float*)d_in[8];
    const float* bp2 = (const float*)d_in[9];
    const float* We1 = (const float*)d_in[10];
    const float* be1 = (const float*)d_in[11];
    const float* We2 = (const float*)d_in[12];
    const float* be2 = (const float*)d_in[13];
    const float* Wa1 = (const float*)d_in[14];
    const float* ba1 = (const float*)d_in[15];
    const float* Wa2 = (const float*)d_in[16];
    const float* ba2 = (const float*)d_in[17];

    float* out = (float*)d_out;
    char*  ws  = (char*)d_ws;
    // ws layout (bytes):
    //   [0,       8192)   wp1t  bf16 128x32
    //   [8192,   40960)   wp2t  bf16 128x128
    //   [40960, 106496)   we1t  bf16 256x128
    //   [106496,368640)   we2t  bf16 512x256
    //   [368640,385024)   pooledL1 f32 8x512
    //   [385024,387072)   pooledR  f32 1x512
    unsigned short* wp1t     = (unsigned short*)ws;
    unsigned short* wp2t     = (unsigned short*)(ws + 8192);
    unsigned short* we1t     = (unsigned short*)(ws + 40960);
    unsigned short* we2t     = (unsigned short*)(ws + 106496);
    float*          pooledL1 = (float*)(ws + 368640);
    float*          pooledR  = (float*)(ws + 385024);

    // leaf rows of out are the atomicMax accumulators; must start at 0
    // (valid: post-relu values >= 0)
    hipMemsetAsync(out + (size_t)(1 + NB1) * DOUT, 0,
                   (size_t)NLEAF * DOUT * sizeof(float), stream);

    convert_weights<<<dim3(720), dim3(256), 0, stream>>>(
        Wp1, Wp2, We1, We2, wp1t, wp2t, we1t, we2t);

    leaf_mfma_kernel<<<dim3(NLEAF * (KPL / TM)), dim3(512), 0, stream>>>(
        coords, feats, leaf_indices, leaf_center_idx,
        wp1t, bp1, wp2t, bp2, we1t, be1, We1, we2t, be2,
        out + (size_t)(1 + NB1) * DOUT);

    // level 1: 8 parents x 8 leaf children
    agg_pool_kernel<<<dim3(NB1 * 8), dim3(256), 0, stream>>>(
        out + (size_t)(1 + NB1) * DOUT, coords, leaf_center_idx, l1_center_idx,
        Wa1, ba1, pooledL1);
    agg_out_kernel<<<dim3(NB1 * 8), dim3(256), 0, stream>>>(
        pooledL1, Wa2, ba2, out + DOUT);

    // root: 1 parent x 8 level-1 children (reads level-1 rows just written)
    agg_pool_kernel<<<dim3(8), dim3(256), 0, stream>>>(
        out + DOUT, coords, l1_center_idx, root_center_idx,
        Wa1, ba1, pooledR);
    agg_out_kernel<<<dim3(8), dim3(256), 0, stream>>>(
        pooledR, Wa2, ba2, out);
}

// Round 13
// 119.315 us; speedup vs baseline: 1.1403x; 1.1403x over previous
//
#include <hip/hip_runtime.h>

#define NPTS   131072
#define CIN    32
#define KPL    2048
#define NLEAF  64
#define NB1    8
#define DPJ    128
#define DHID   256
#define DOUT   512
#define TM     128         // points per block in the leaf kernel

typedef __attribute__((ext_vector_type(8))) short  short8;
typedef __attribute__((ext_vector_type(4))) float  f32x4;

// round-to-nearest-even f32 -> bf16
__device__ __forceinline__ unsigned short f2bf(float x) {
    unsigned u = __float_as_uint(x);
    u += 0x7FFFu + ((u >> 16) & 1u);
    return (unsigned short)(u >> 16);
}

// ---------------------------------------------------------------------------
// Weight conversion pre-pass: f32 (K x N) -> bf16 transposed (N x K)
//   wp1t[128][32], wp2t[128][128], we1t[256][128] (rows 3..130 of We1), we2t[512][256]
// ---------------------------------------------------------------------------
__global__ __launch_bounds__(256) void convert_weights(
    const float* __restrict__ Wp1, const float* __restrict__ Wp2,
    const float* __restrict__ We1, const float* __restrict__ We2,
    unsigned short* __restrict__ wp1t, unsigned short* __restrict__ wp2t,
    unsigned short* __restrict__ we1t, unsigned short* __restrict__ we2t)
{
    int idx = blockIdx.x * 256 + threadIdx.x;
    if (idx < 4096) {                       // Wp1: 32 x 128
        int n = idx / 32, k = idx % 32;
        wp1t[idx] = f2bf(Wp1[k * DPJ + n]);
    } else if (idx < 20480) {               // Wp2: 128 x 128
        int i = idx - 4096;
        int n = i / 128, k = i % 128;
        wp2t[i] = f2bf(Wp2[k * DPJ + n]);
    } else if (idx < 53248) {               // We1 rows 3..130: 128 x 256
        int i = idx - 20480;
        int n = i / 128, k = i % 128;
        we1t[i] = f2bf(We1[(k + 3) * DHID + n]);
    } else if (idx < 184320) {              // We2: 256 x 512
        int i = idx - 53248;
        int n = i / 256, k = i % 256;
        we2t[i] = f2bf(We2[k * DOUT + n]);
    }
}

// ---------------------------------------------------------------------------
// MFMA GEMM core: acc[MF][NF] (+bias) += A(LDS, swizzled bf16) @ Wt(global, N x K bf16)
// A-frag: row = 16m + (lane&15), k contiguous.  B-frag: col = cb + 16n + (lane&15).
// Plain loads: R6 proved the compiler already hoists all B-loads of a fully
// unrolled call into one issue group (explicit 2-slot pipeline was NULL).
// ---------------------------------------------------------------------------
template<int MF, int NF, int KSTEPS, int SB, int WK>
__device__ __forceinline__ void gemm_core(
    const char* sIn, const unsigned short* __restrict__ wt,
    const float* __restrict__ bias, int cb, int lr, int lg, f32x4 acc[MF][NF])
{
    #pragma unroll
    for (int n = 0; n < NF; ++n) {
        float bv = bias[cb + 16 * n + lr];
        #pragma unroll
        for (int m = 0; m < MF; ++m) acc[m][n] = f32x4{bv, bv, bv, bv};
    }
    #pragma unroll
    for (int kk = 0; kk < KSTEPS; ++kk) {
        short8 b[NF];
        #pragma unroll
        for (int n = 0; n < NF; ++n)
            b[n] = *reinterpret_cast<const short8*>(
                wt + (size_t)(cb + 16 * n + lr) * WK + kk * 32 + lg * 8);
        #pragma unroll
        for (int m = 0; m < MF; ++m) {
            int row  = 16 * m + lr;
            int byte = (row * SB + kk * 64 + lg * 16) ^ ((row & 7) << 4);
            short8 a = *reinterpret_cast<const short8*>(sIn + byte);
            #pragma unroll
            for (int n = 0; n < NF; ++n)
                acc[m][n] = __builtin_amdgcn_mfma_f32_16x16x32_bf16(a, b[n], acc[m][n], 0, 0, 0);
        }
    }
}

// store acc to swizzled bf16 LDS buffer; D mapping row = 16m + lg*4 + r, col = cb+16n+lr
template<int MF, int NF, int SB, bool RELU>
__device__ __forceinline__ void store_frag(char* sOut, int cb, int lr, int lg, f32x4 acc[MF][NF])
{
    #pragma unroll
    for (int m = 0; m < MF; ++m) {
        #pragma unroll
        for (int r = 0; r < 4; ++r) {
            int row = 16 * m + lg * 4 + r;
            int rb  = row * SB;
            int sw  = (row & 7) << 4;
            #pragma unroll
            for (int n = 0; n < NF; ++n) {
                float v = acc[m][n][r];
                if (RELU) v = fmaxf(v, 0.f);
                int byte = (rb + (cb + 16 * n + lr) * 2) ^ sw;
                *reinterpret_cast<unsigned short*>(sOut + byte) = f2bf(v);
            }
        }
    }
}

// max-reduce an acc[MF][NF] block over rows and write to leaf accumulator
template<int MF, int NF>
__device__ __forceinline__ void pool_frag(float* dst, int cb, int lr, int lg, f32x4 acc[MF][NF])
{
    #pragma unroll
    for (int n = 0; n < NF; ++n) {
        float vm = 0.f;   // relu folded into max with 0
        #pragma unroll
        for (int m = 0; m < MF; ++m) {
            #pragma unroll
            for (int r = 0; r < 4; ++r) vm = fmaxf(vm, acc[m][n][r]);
        }
        vm = fmaxf(vm, __shfl_xor(vm, 16));
        vm = fmaxf(vm, __shfl_xor(vm, 32));
        if (lg == 0)
            atomicMax(reinterpret_cast<int*>(dst + cb + 16 * n + lr),
                      __float_as_int(vm));
    }
}

// ---------------------------------------------------------------------------
// Fused per-point pipeline + leaf max-pool, bf16 MFMA.
// grid = NLEAF * (KPL/TM) = 1024 blocks, 256 threads (4 waves, N-split).
// R12 falsified in-block wave parallelism (2 waves/SIMD lockstep: -15%).
// R11 (this base) runs 1 block/CU, 1 wave/SIMD; per-slot cost ~ SUM of pipe
// times (no overlap within a single serial wave). This round merges the
// NF=2 passes (spill-cap-era relic) into NF=4 calls: stage 3 = 1 call,
// stage 4 = 2 calls. Per wave: stage-4 A-reads 256->128, B-latency bursts
// 8->5, 32 independent MFMAs per kk for the scheduler. acc peak 128 AGPR
// (+hoisted B) ~ 330-400 total regs: legal at 256 thr (m08: no spill <=450),
// and occupancy can't drop (LDS 101 KB binds at 1 block/CU regardless).
// ---------------------------------------------------------------------------
__global__ __launch_bounds__(256, 1) void leaf_mfma_kernel(
    const float* __restrict__ coords, const float* __restrict__ feats,
    const int* __restrict__ leaf_indices, const int* __restrict__ leaf_center_idx,
    const unsigned short* __restrict__ wp1t, const float* __restrict__ bp1,
    const unsigned short* __restrict__ wp2t, const float* __restrict__ bp2,
    const unsigned short* __restrict__ we1t, const float* __restrict__ be1,
    const float* __restrict__ We1raw,
    const unsigned short* __restrict__ we2t, const float* __restrict__ be2,
    float* __restrict__ leaf_out)              // = out + (1+NB1)*DOUT, zero-initialized
{
    __shared__ __align__(16) char bufH [TM * DHID * 2];   // 64 KB
    __shared__ __align__(16) char bufP2[TM * DPJ * 2];    // 32 KB
    __shared__ float s_rel[TM][4];                        // 2 KB
    __shared__ float s_we1rel[3 * DHID];                  // 3 KB

    const int t    = threadIdx.x;
    const int lane = t & 63;
    const int w    = t >> 6;       // wave id 0..3 (N-split)
    const int lr   = lane & 15;
    const int lg   = lane >> 4;

    const int l     = blockIdx.x >> 4;          // leaf (16 chunks/leaf)
    const int chunk = blockIdx.x & 15;
    const int base  = l * KPL + chunk * TM;

    // stage features -> bf16 LDS (swizzled): 256 threads, 32B (16 ch) per thread
    {
        const int p  = t >> 1;          // 0..127
        const int kq = (t & 1) << 4;    // 0 or 16
        const int gi = leaf_indices[base + p];
        const float* src = feats + (size_t)gi * CIN + kq;
        float4 v0 = *reinterpret_cast<const float4*>(src);
        float4 v1 = *reinterpret_cast<const float4*>(src + 4);
        float4 v2 = *reinterpret_cast<const float4*>(src + 8);
        float4 v3 = *reinterpret_cast<const float4*>(src + 12);
        short8 o0, o1;
        o0[0] = (short)f2bf(v0.x); o0[1] = (short)f2bf(v0.y);
        o0[2] = (short)f2bf(v0.z); o0[3] = (short)f2bf(v0.w);
        o0[4] = (short)f2bf(v1.x); o0[5] = (short)f2bf(v1.y);
        o0[6] = (short)f2bf(v1.z); o0[7] = (short)f2bf(v1.w);
        o1[0] = (short)f2bf(v2.x); o1[1] = (short)f2bf(v2.y);
        o1[2] = (short)f2bf(v2.z); o1[3] = (short)f2bf(v2.w);
        o1[4] = (short)f2bf(v3.x); o1[5] = (short)f2bf(v3.y);
        o1[6] = (short)f2bf(v3.z); o1[7] = (short)f2bf(v3.w);
        const int sw = (p & 7) << 4;
        int b0 = (p * (CIN * 2) + kq * 2) ^ sw;
        int b1 = (p * (CIN * 2) + kq * 2 + 16) ^ sw;
        *reinterpret_cast<short8*>(bufH + b0) = o0;
        *reinterpret_cast<short8*>(bufH + b1) = o1;
    }
    if (t < TM) {
        const int gi = leaf_indices[base + t];
        const int ci = leaf_center_idx[l];
        s_rel[t][0] = coords[gi * 3 + 0] - coords[ci * 3 + 0];
        s_rel[t][1] = coords[gi * 3 + 1] - coords[ci * 3 + 1];
        s_rel[t][2] = coords[gi * 3 + 2] - coords[ci * 3 + 2];
    }
    #pragma unroll
    for (int j = 0; j < 3; ++j) s_we1rel[j * DHID + t] = We1raw[j * DHID + t];
    __syncthreads();

    // ---- Stage 1: P1 = relu(X @ Wp1 + bp1)   (128x128, K=32; 32 cols/wave) ----
    {
        f32x4 acc[8][2];
        gemm_core<8, 2, 1, CIN * 2, 32>(bufH, wp1t, bp1, w * 32, lr, lg, acc);
        store_frag<8, 2, DPJ * 2, true>(bufH + TM * CIN * 2, w * 32, lr, lg, acc);
    }
    __syncthreads();

    // ---- Stage 2: P2 = P1 @ Wp2 + bp2        (128x128, K=128; 32 cols/wave) ----
    {
        f32x4 acc[8][2];
        gemm_core<8, 2, 4, DPJ * 2, 128>(bufH + TM * CIN * 2, wp2t, bp2, w * 32, lr, lg, acc);
        store_frag<8, 2, DPJ * 2, false>(bufP2, w * 32, lr, lg, acc);
    }
    __syncthreads();

    // ---- Stage 3: H = relu([rel,P2] @ We1 + be1)  (128x256, K=3+128; 64 cols/wave) ----
    // single call NF=4 (acc 128): one B-burst, A reused across 4 cols
    {
        const int cb = w * 64;
        f32x4 acc[8][4];
        gemm_core<8, 4, 4, DPJ * 2, 128>(bufP2, we1t, be1, cb, lr, lg, acc);
        // rel (K=3) contribution on VALU
        #pragma unroll
        for (int m = 0; m < 8; ++m) {
            #pragma unroll
            for (int r = 0; r < 4; ++r) {
                int row = 16 * m + lg * 4 + r;
                float r0 = s_rel[row][0], r1 = s_rel[row][1], r2 = s_rel[row][2];
                #pragma unroll
                for (int n = 0; n < 4; ++n) {
                    int col = cb + 16 * n + lr;
                    acc[m][n][r] += r0 * s_we1rel[col]
                                  + r1 * s_we1rel[DHID + col]
                                  + r2 * s_we1rel[2 * DHID + col];
                }
            }
        }
        store_frag<8, 4, DHID * 2, true>(bufH, cb, lr, lg, acc);
    }
    __syncthreads();

    // ---- Stage 4: out = relu(H @ We2 + be2) (128x512, K=256; 128 cols/wave) ----
    // two passes of NF=4 (acc 128): A-reads halve, B-bursts 4->2
    {
        float* const dst = leaf_out + (size_t)l * DOUT;
        #pragma unroll
        for (int p4 = 0; p4 < 2; ++p4) {
            const int cb = w * 128 + p4 * 64;
            f32x4 acc[8][4];
            gemm_core<8, 4, 8, DHID * 2, 256>(bufH, we2t, be2, cb, lr, lg, acc);
            pool_frag<8, 4>(dst, cb, lr, lg, acc);
        }
    }
}

// ---------------------------------------------------------------------------
// Aggregator, phase 1 (pool): pooled[p][col] = max_m relu(z_m . Wa1[:,col] + ba1[col])
//   z_m = [child[p*8+m][0:512], coords[child_idx[p*8+m]] - coords[parent_idx[p]]]
// grid = nparent*8 blocks (8 col-chunks of 64), 256 threads (4-way K split).
// ---------------------------------------------------------------------------
__global__ __launch_bounds__(256) void agg_pool_kernel(
    const float* __restrict__ child,      // [nparent*8][512]
    const float* __restrict__ coords,
    const int* __restrict__ child_idx,    // [nparent*8]
    const int* __restrict__ parent_idx,   // [nparent]
    const float* __restrict__ Wa1, const float* __restrict__ ba1,
    float* __restrict__ pooled)           // [nparent][512]
{
    __shared__ float s_z[NB1][516];       // 8 children x (512 feat + 3 rel)
    __shared__ float s_red[4][NB1][64];

    const int t  = threadIdx.x;
    const int b  = blockIdx.x;
    const int p  = b >> 3, cc = b & 7;
    const int c  = t & 63;
    const int col = cc * 64 + c;
    const int ks = t >> 6;                // K-slice 0..3

    {   // stage child features (8 x 512 f32)
        const int m = t >> 5, tt = t & 31;
        const float* src = child + (size_t)(p * NB1 + m) * DOUT;
        #pragma unroll
        for (int i = 0; i < 4; ++i) {
            const int idx = (i * 32 + tt) * 4;
            *reinterpret_cast<float4*>(&s_z[m][idx]) =
                *reinterpret_cast<const float4*>(src + idx);
        }
    }
    if (t < 24) {                         // rel coords into rows 512..514
        const int m = t / 3, j = t % 3;
        s_z[m][512 + j] = coords[child_idx[p * NB1 + m] * 3 + j]
                        - coords[parent_idx[p] * 3 + j];
    }
    __syncthreads();

    float acc[NB1] = {0.f, 0.f, 0.f, 0.f, 0.f, 0.f, 0.f, 0.f};
    const int k0 = ks * 128;
    #pragma unroll 32
    for (int i = 0; i < 128; ++i) {
        const int k = k0 + i;
        const float wv = Wa1[(size_t)k * DOUT + col];
        #pragma unroll
        for (int m = 0; m < NB1; ++m) acc[m] += s_z[m][k] * wv;
    }
    if (ks == 3) {                        // rel rows 512..514
        #pragma unroll
        for (int k = 512; k < 515; ++k) {
            const float wv = Wa1[(size_t)k * DOUT + col];
            #pragma unroll
            for (int m = 0; m < NB1; ++m) acc[m] += s_z[m][k] * wv;
        }
    }
    #pragma unroll
    for (int m = 0; m < NB1; ++m) s_red[ks][m][c] = acc[m];
    __syncthreads();

    if (t < 64) {
        const float bv = ba1[col];
        float pm = 0.f;                   // relu folded into max with 0
        #pragma unroll
        for (int m = 0; m < NB1; ++m) {
            float v = bv + s_red[0][m][c] + s_red[1][m][c]
                         + s_red[2][m][c] + s_red[3][m][c];
            pm = fmaxf(pm, v);
        }
        pooled[(size_t)p * DOUT + col] = pm;
    }
}

// ---------------------------------------------------------------------------
// Aggregator, phase 2 (matvec): outrow[p][col] = pooled[p] . Wa2[:,col] + ba2[col]
// grid = nparent*8 blocks, 256 threads (4-way K split).
// ---------------------------------------------------------------------------
__global__ __launch_bounds__(256) void agg_out_kernel(
    const float* __restrict__ pooled,     // [nparent][512]
    const float* __restrict__ Wa2, const float* __restrict__ ba2,
    float* __restrict__ outbase)          // row p at outbase + p*DOUT
{
    __shared__ float s_p[DOUT];
    __shared__ float s_red[4][64];

    const int t  = threadIdx.x;
    const int b  = blockIdx.x;
    const int p  = b >> 3, cc = b & 7;
    const int c  = t & 63;
    const int col = cc * 64 + c;
    const int ks = t >> 6;

    if (t < 128)
        *reinterpret_cast<float4*>(&s_p[t * 4]) =
            *reinterpret_cast<const float4*>(pooled + (size_t)p * DOUT + t * 4);
    __syncthreads();

    float acc = 0.f;
    const int k0 = ks * 128;
    #pragma unroll 32
    for (int i = 0; i < 128; ++i) {
        const int k = k0 + i;
        acc += s_p[k] * Wa2[(size_t)k * DOUT + col];
    }
    s_red[ks][c] = acc;
    __syncthreads();

    if (t < 64)
        outbase[(size_t)p * DOUT + col] =
            ba2[col] + s_red[0][c] + s_red[1][c] + s_red[2][c] + s_red[3][c];
}

extern "C" void kernel_launch(void* const* d_in, const int* in_sizes, int n_in,
                              void* d_out, int out_size, void* d_ws, size_t ws_size,
                              hipStream_t stream)
{
    const float* coords          = (const float*)d_in[0];
    const float* feats           = (const float*)d_in[1];
    const int*   leaf_indices    = (const int*)d_in[2];
    const int*   leaf_center_idx = (const int*)d_in[3];
    const int*   l1_center_idx   = (const int*)d_in[4];
    const int*   root_center_idx = (const int*)d_in[5];
    const float* Wp1 = (const float*)d_in[6];
    const float* bp1 = (const float*)d_in[7];
    const float* Wp2 = (const float*)d_in[8];
    const float* bp2 = (const float*)d_in[9];
    const float* We1 = (const float*)d_in[10];
    const float* be1 = (const float*)d_in[11];
    const float* We2 = (const float*)d_in[12];
    const float* be2 = (const float*)d_in[13];
    const float* Wa1 = (const float*)d_in[14];
    const float* ba1 = (const float*)d_in[15];
    const float* Wa2 = (const float*)d_in[16];
    const float* ba2 = (const float*)d_in[17];

    float* out = (float*)d_out;
    char*  ws  = (char*)d_ws;
    // ws layout (bytes):
    //   [0,       8192)   wp1t  bf16 128x32
    //   [8192,   40960)   wp2t  bf16 128x128
    //   [40960, 106496)   we1t  bf16 256x128
    //   [106496,368640)   we2t  bf16 512x256
    //   [368640,385024)   pooledL1 f32 8x512
    //   [385024,387072)   pooledR  f32 1x512
    unsigned short* wp1t     = (unsigned short*)ws;
    unsigned short* wp2t     = (unsigned short*)(ws + 8192);
    unsigned short* we1t     = (unsigned short*)(ws + 40960);
    unsigned short* we2t     = (unsigned short*)(ws + 106496);
    float*          pooledL1 = (float*)(ws + 368640);
    float*          pooledR  = (float*)(ws + 385024);

    // leaf rows of out are the atomicMax accumulators; must start at 0
    // (valid: post-relu values >= 0)
    hipMemsetAsync(out + (size_t)(1 + NB1) * DOUT, 0,
                   (size_t)NLEAF * DOUT * sizeof(float), stream);

    convert_weights<<<dim3(720), dim3(256), 0, stream>>>(
        Wp1, Wp2, We1, We2, wp1t, wp2t, we1t, we2t);

    leaf_mfma_kernel<<<dim3(NLEAF * (KPL / TM)), dim3(256), 0, stream>>>(
        coords, feats, leaf_indices, leaf_center_idx,
        wp1t, bp1, wp2t, bp2, we1t, be1, We1, we2t, be2,
        out + (size_t)(1 + NB1) * DOUT);

    // level 1: 8 parents x 8 leaf children
    agg_pool_kernel<<<dim3(NB1 * 8), dim3(256), 0, stream>>>(
        out + (size_t)(1 + NB1) * DOUT, coords, leaf_center_idx, l1_center_idx,
        Wa1, ba1, pooledL1);
    agg_out_kernel<<<dim3(NB1 * 8), dim3(256), 0, stream>>>(
        pooledL1, Wa2, ba2, out + DOUT);

    // root: 1 parent x 8 level-1 children (reads level-1 rows just written)
    agg_pool_kernel<<<dim3(8), dim3(256), 0, stream>>>(
        out + DOUT, coords, l1_center_idx, root_center_idx,
        Wa1, ba1, pooledR);
    agg_out_kernel<<<dim3(8), dim3(256), 0, stream>>>(
        pooledR, Wa2, ba2, out);
}